// Round 9
// baseline (5763.613 us; speedup 1.0000x reference)
//
#include <hip/hip_runtime.h>
#include <math.h>

// TemporalDecoder round 9: R8 with the xcvt OOB fixed (grid was 2x the element
// count -> 67MB of stray writes -> HSA memory fault). Grid now derived from
// in_sizes[0] with an in-kernel guard. Kernel-side design unchanged from R8:
// - store + per-wave __all() scan grid barrier (no hidden LDS)
// - vectorized 8B h-exchange stores (shfl-packed 4 hcols)
// - decode fc fused via Wcomb = Wih0@Wout (decode: 2 phases/step, 63 barriers)
// - x pre-converted to f16; depth-3 load ring; raw s_barrier in the K-loop

#define BB 256
#define SS 128
#define HH 512
#define NSTEPS 32

typedef __attribute__((ext_vector_type(8))) _Float16 f16x8;
typedef __attribute__((ext_vector_type(4))) float f32x4;

#define LO_SCALE 2048.0f
#define LO_INV   (1.0f / 2048.0f)
#define AGENT __HIP_MEMORY_SCOPE_AGENT

__device__ __forceinline__ uint2 ld_agent_u2(const uint2* p) {
    return __hip_atomic_load(p, __ATOMIC_RELAXED, AGENT);
}
__device__ __forceinline__ void st_agent_u64(unsigned long long* p, unsigned long long v) {
    __hip_atomic_store(p, v, __ATOMIC_RELAXED, AGENT);
}

// Raw WG barrier: LDS ordering only, leaves global loads in flight.
__device__ __forceinline__ void wg_barrier() {
    __builtin_amdgcn_sched_barrier(0);
    asm volatile("s_waitcnt lgkmcnt(0)" ::: "memory");
    __builtin_amdgcn_s_barrier();
    asm volatile("" ::: "memory");
    __builtin_amdgcn_sched_barrier(0);
}

// ---------------- prep kernels ------------------------------------------------
__global__ __launch_bounds__(256) void xcvt(const float* __restrict__ x,
                                            ushort* __restrict__ xh, int n8) {
    int t = blockIdx.x * 256 + threadIdx.x;
    if (t >= n8) return;
    size_t i = (size_t)t * 8;
    float4 a = *(const float4*)(x + i), b = *(const float4*)(x + i + 4);
    union { _Float16 h[8]; uint4 u; } P;
    P.h[0] = (_Float16)a.x; P.h[1] = (_Float16)a.y;
    P.h[2] = (_Float16)a.z; P.h[3] = (_Float16)a.w;
    P.h[4] = (_Float16)b.x; P.h[5] = (_Float16)b.y;
    P.h[6] = (_Float16)b.z; P.h[7] = (_Float16)b.w;
    *(uint4*)(xh + i) = P.u;
}

__global__ __launch_bounds__(256) void wsplit_layers(
    const float* __restrict__ W_ih, const float* __restrict__ W_hh,
    ushort* __restrict__ wf0, ushort* __restrict__ wf1)
{
    int f = blockIdx.x * 256 + threadIdx.x;      // 0..524287
    int L = f >> 18;
    int t = f & 262143;
    int lane = t & 63;
    int kfg = (t >> 6) & 31;
    int nfrag = t >> 11;                         // 0..127
    int nloc = (nfrag & 1) * 16 + (lane & 15);
    int g = nloc & 3, hc = nloc >> 2;
    int n_W = g * 512 + (nfrag >> 1) * 8 + hc;
    int mat = kfg >> 4;
    int klocal = (kfg & 15) * 32 + (lane >> 4) * 8;
    const float* src = (mat ? W_hh : W_ih) + (size_t)L * (2048 * 512)
                       + (size_t)n_W * 512 + klocal;
    float4 a = *(const float4*)src;
    float4 b = *(const float4*)(src + 4);
    float v[8] = {a.x, a.y, a.z, a.w, b.x, b.y, b.z, b.w};
    union { _Float16 h[8]; uint4 u; } Hi, Lo;
    #pragma unroll
    for (int j = 0; j < 8; ++j) {
        Hi.h[j] = (_Float16)v[j];
        Lo.h[j] = (_Float16)((v[j] - (float)Hi.h[j]) * LO_SCALE);
    }
    ushort* dst = L ? wf1 : wf0;
    size_t b0 = (((size_t)nfrag * 2 + 0) * 32 + kfg) * 512 + lane * 8;
    size_t b1 = (((size_t)nfrag * 2 + 1) * 32 + kfg) * 512 + lane * 8;
    *(uint4*)(dst + b0) = Hi.u;
    *(uint4*)(dst + b1) = Lo.u;
}

__global__ __launch_bounds__(256) void wsplit_out(
    const float* __restrict__ W_out, ushort* __restrict__ wfO)
{
    int f = blockIdx.x * 256 + threadIdx.x;      // 0..32767
    int lane = f & 63;
    int kfg = (f >> 6) & 15;
    int nfrag = f >> 10;                         // 0..31
    int n_W = nfrag * 16 + (lane & 15);
    int klocal = kfg * 32 + (lane >> 4) * 8;
    const float* src = W_out + (size_t)n_W * 512 + klocal;
    float4 a = *(const float4*)src;
    float4 b = *(const float4*)(src + 4);
    float v[8] = {a.x, a.y, a.z, a.w, b.x, b.y, b.z, b.w};
    union { _Float16 h[8]; uint4 u; } Hi, Lo;
    #pragma unroll
    for (int j = 0; j < 8; ++j) {
        Hi.h[j] = (_Float16)v[j];
        Lo.h[j] = (_Float16)((v[j] - (float)Hi.h[j]) * LO_SCALE);
    }
    size_t b0 = (((size_t)nfrag * 2 + 0) * 16 + kfg) * 512 + lane * 8;
    size_t b1 = (((size_t)nfrag * 2 + 1) * 16 + kfg) * 512 + lane * 8;
    *(uint4*)(wfO + b0) = Hi.u;
    *(uint4*)(wfO + b1) = Lo.u;
}

// Wcomb = Wih0 @ Wout  (fp32, [2048,512] = [2048,512]@[512,512])
__global__ __launch_bounds__(256) void gemm_wcomb(
    const float* __restrict__ A, const float* __restrict__ Bm, float* __restrict__ C)
{
    __shared__ float sAf[64][17];
    __shared__ float sBf[16][65];
    const int tid = threadIdx.x;
    const int tx = tid & 15, ty = tid >> 4;
    const int n0 = blockIdx.x * 64, h0 = blockIdx.y * 64;
    float acc[4][4] = {};
    #pragma unroll 1
    for (int k0 = 0; k0 < 512; k0 += 16) {
        __syncthreads();
        {
            int r = tid >> 2, c = (tid & 3) * 4;
            float4 v = *(const float4*)&A[(size_t)(n0 + r) * 512 + k0 + c];
            sAf[r][c] = v.x; sAf[r][c + 1] = v.y; sAf[r][c + 2] = v.z; sAf[r][c + 3] = v.w;
        }
        {
            int r = tid >> 4, c = (tid & 15) * 4;
            float4 v = *(const float4*)&Bm[(size_t)(k0 + r) * 512 + h0 + c];
            sBf[r][c] = v.x; sBf[r][c + 1] = v.y; sBf[r][c + 2] = v.z; sBf[r][c + 3] = v.w;
        }
        __syncthreads();
        #pragma unroll
        for (int kk = 0; kk < 16; ++kk) {
            #pragma unroll
            for (int a_ = 0; a_ < 4; ++a_) {
                float av = sAf[ty + 16 * a_][kk];
                #pragma unroll
                for (int b_ = 0; b_ < 4; ++b_)
                    acc[a_][b_] += av * sBf[kk][tx + 16 * b_];
            }
        }
    }
    #pragma unroll
    for (int a_ = 0; a_ < 4; ++a_)
        #pragma unroll
        for (int b_ = 0; b_ < 4; ++b_)
            C[(size_t)(n0 + ty + 16 * a_) * 512 + h0 + tx + 16 * b_] = acc[a_][b_];
}

__global__ __launch_bounds__(256) void bcomb_k(const float* __restrict__ Wih0,
                                               const float* __restrict__ bout,
                                               float* __restrict__ bc) {
    int n = blockIdx.x * 256 + threadIdx.x;
    float a = 0.f;
    for (int f = 0; f < 512; ++f) a += Wih0[(size_t)n * 512 + f] * bout[f];
    bc[n] = a;
}

// split Wcomb to frag order (mirrors wf0's Wih half: kfg 0..15)
__global__ __launch_bounds__(256) void wsplit_wcomb(
    const float* __restrict__ wc, ushort* __restrict__ wfC)
{
    int f = blockIdx.x * 256 + threadIdx.x;      // 0..131071
    int lane = f & 63;
    int kfg = (f >> 6) & 15;
    int nfrag = f >> 10;                         // 0..127
    int nloc = (nfrag & 1) * 16 + (lane & 15);
    int g = nloc & 3, hc = nloc >> 2;
    int n_W = g * 512 + (nfrag >> 1) * 8 + hc;
    int klocal = kfg * 32 + (lane >> 4) * 8;
    const float* src = wc + (size_t)n_W * 512 + klocal;
    float4 a = *(const float4*)src;
    float4 b = *(const float4*)(src + 4);
    float v[8] = {a.x, a.y, a.z, a.w, b.x, b.y, b.z, b.w};
    union { _Float16 h[8]; uint4 u; } Hi, Lo;
    #pragma unroll
    for (int j = 0; j < 8; ++j) {
        Hi.h[j] = (_Float16)v[j];
        Lo.h[j] = (_Float16)((v[j] - (float)Hi.h[j]) * LO_SCALE);
    }
    size_t b0 = (((size_t)nfrag * 2 + 0) * 16 + kfg) * 512 + lane * 8;
    size_t b1 = (((size_t)nfrag * 2 + 1) * 16 + kfg) * 512 + lane * 8;
    *(uint4*)(wfC + b0) = Hi.u;
    *(uint4*)(wfC + b1) = Lo.u;
}

// ---------------- grid barrier: store + per-wave __all scan (no LDS) ----------
__device__ __forceinline__ void gridbar(unsigned* slots, unsigned phase)
{
    __syncthreads();   // drains vmcnt: this WG's h-stores acked at LLC
    if (threadIdx.x == 0)
        __hip_atomic_store(&slots[blockIdx.x], phase, __ATOMIC_RELAXED, AGENT);
    // thread tid polls slots[tid]; the 4 waves partition all 256 slots.
    unsigned v;
    do {
        v = __hip_atomic_load(&slots[threadIdx.x], __ATOMIC_RELAXED, AGENT);
    } while (!__all((int)(v >= phase)));
    __syncthreads();
}

// ---------------- LSTM cell (M=128 x N=32 gate-cols, K=1024) ------------------
static __device__ __forceinline__ void run_cell(
    const int tid, const int mblk, const int hcblk,
    const ushort* __restrict__ Asrc, const size_t ldA,
    const ushort* __restrict__ Hprev,
    ushort (*sW)[2][32][512], ushort (*sA)[128][64],
    float (&cReg)[16], const float bias, ushort* __restrict__ Hout)
{
    const int lane = tid & 63, wid = tid >> 6;
    const int wm = wid >> 1, wn = wid & 1;
    const int lr = lane & 15, lq = lane >> 4;

    f32x4 acch[4], accl[4];
    #pragma unroll
    for (int i = 0; i < 4; ++i) {
        acch[i] = (f32x4){bias, bias, bias, bias};
        accl[i] = (f32x4){0.f, 0.f, 0.f, 0.f};
    }

    const int srow = tid >> 1;
    const int cbase = (tid & 1) * 4;
    uint2 ur[3][8];

    auto ld = [&](int it) {
        const int k0 = (it & 7) * 64;
        const ushort* s = (it < 8)
            ? (Asrc + (size_t)(mblk * 128 + srow) * ldA + k0 + cbase * 8)
            : (Hprev + (size_t)(mblk * 128 + srow) * 512 + k0 + cbase * 8);
        const uint2* s2 = (const uint2*)s;
        uint2* u = ur[it % 3];
        #pragma unroll
        for (int c = 0; c < 8; ++c) u[c] = ld_agent_u2(s2 + c);
    };
    auto wr = [&](int it) {
        const uint2* u = ur[it % 3];
        ushort (*dst)[64] = sA[it & 1];
        #pragma unroll
        for (int c = 0; c < 4; ++c) {
            uint4 wv;
            wv.x = u[2 * c].x;     wv.y = u[2 * c].y;
            wv.z = u[2 * c + 1].x; wv.w = u[2 * c + 1].y;
            *(uint4*)&dst[srow][((cbase + c) ^ (srow & 7)) * 8] = wv;
        }
    };
    auto compute = [&](int it) {
        ushort (*buf)[64] = sA[it & 1];
        #pragma unroll
        for (int kf = 0; kf < 2; ++kf) {
            const int kfg = it * 2 + kf;
            const f16x8 bh = *(const f16x8*)&sW[wn][0][kfg][lane * 8];
            const f16x8 bl = *(const f16x8*)&sW[wn][1][kfg][lane * 8];
            #pragma unroll
            for (int mf = 0; mf < 4; ++mf) {
                const int row = wm * 64 + mf * 16 + lr;
                const int cg = kf * 4 + lq;
                const f16x8 a = *(const f16x8*)&buf[row][(cg ^ (row & 7)) * 8];
                acch[mf] = __builtin_amdgcn_mfma_f32_16x16x32_f16(a, bh, acch[mf], 0, 0, 0);
                accl[mf] = __builtin_amdgcn_mfma_f32_16x16x32_f16(a, bl, accl[mf], 0, 0, 0);
            }
        }
    };

    ld(0); ld(1); ld(2);
    wr(0);
    #pragma unroll
    for (int it = 0; it < 16; ++it) {
        wg_barrier();                    // sA[it&1] ready; ring loads stay in flight
        if (it + 3 < 16) ld(it + 3);
        compute(it);
        if (it + 1 < 16) wr(it + 1);     // vmcnt wait sits after compute
    }

    // epilogue: all 4 gate-lanes compute identical (cn,hn); pack 4 hcols -> 8B store
    const int nloc = wn * 16 + lr;
    const int g = nloc & 3;
    const int colbase = hcblk * 8 + wn * 4;
    #pragma unroll
    for (int mf = 0; mf < 4; ++mf) {
        #pragma unroll
        for (int j = 0; j < 4; ++j) {
            float v = acch[mf][j] + accl[mf][j] * LO_INV;
            float s1 = __shfl_xor(v, 1, 64);
            float s2 = __shfl_xor(v, 2, 64);
            float s3 = __shfl_xor(v, 3, 64);
            float sel0 = v;
            auto selk = [&](int k) {
                return (k == 0) ? sel0 : (k == 1) ? s1 : (k == 2) ? s2 : s3;
            };
            float pi = selk(g), pf = selk(g ^ 1), pg = selk(g ^ 2), po = selk(g ^ 3);
            float ig = 1.f / (1.f + __expf(-pi));
            float fg = 1.f / (1.f + __expf(-pf));
            float e2g = __expf(2.f * fminf(fmaxf(pg, -20.f), 20.f));
            float gg = (e2g - 1.f) / (e2g + 1.f);
            float og = 1.f / (1.f + __expf(-po));
            float cn = fg * cReg[mf * 4 + j] + ig * gg;
            cReg[mf * 4 + j] = cn;
            float e2c = __expf(2.f * fminf(fmaxf(cn, -20.f), 20.f));
            float th = (e2c - 1.f) / (e2c + 1.f);
            float hn = og * th;
            union { _Float16 h; ushort u; } P;
            P.h = (_Float16)hn;
            int hb = (int)P.u;
            int base = lane & ~15;
            int b1 = __shfl(hb, base + 4, 64);
            int b2 = __shfl(hb, base + 8, 64);
            int b3 = __shfl(hb, base + 12, 64);
            if (lr == 0) {
                unsigned long long pk =
                    (unsigned long long)(unsigned)(hb & 0xFFFF)
                    | ((unsigned long long)(unsigned)(b1 & 0xFFFF) << 16)
                    | ((unsigned long long)(unsigned)(b2 & 0xFFFF) << 32)
                    | ((unsigned long long)(unsigned)(b3 & 0xFFFF) << 48);
                int row = mblk * 128 + wm * 64 + mf * 16 + lq * 4 + j;
                st_agent_u64((unsigned long long*)&Hout[(size_t)row * 512 + colbase], pk);
            }
        }
    }
}

// ---------------- fc: out[:,s] = h1 @ Wout^T + bout (half1 WGs, decode) -------
static __device__ __forceinline__ void run_fc(
    const int tid, const int w,
    const ushort* __restrict__ h1, const ushort* __restrict__ wfO,
    const float* __restrict__ b_out, float* __restrict__ out, const int s)
{
    const int lane = tid & 63, wid = tid >> 6;
    const int wm = wid >> 1, wn = wid & 1;
    const int lr = lane & 15, lq = lane >> 4;
    const int fm = w & 7, fn = w >> 3;
    const int nfrag = fn * 2 + wn;
    const int col = nfrag * 16 + lr;
    const int arow = fm * 32 + wm * 16 + lr;

    float bv = b_out[col];
    f32x4 acch = (f32x4){bv, bv, bv, bv};
    f32x4 accl = (f32x4){0.f, 0.f, 0.f, 0.f};

    uint2 au[32];
    #pragma unroll
    for (int kfg = 0; kfg < 16; ++kfg) {
        const uint2* sp = (const uint2*)&h1[(size_t)arow * 512 + kfg * 32 + lq * 8];
        au[2 * kfg]     = ld_agent_u2(sp);
        au[2 * kfg + 1] = ld_agent_u2(sp + 1);
    }
    #pragma unroll
    for (int kfg = 0; kfg < 16; ++kfg) {
        union { uint2 u[2]; f16x8 v; } A;
        A.u[0] = au[2 * kfg]; A.u[1] = au[2 * kfg + 1];
        const f16x8 bh = *(const f16x8*)&wfO[(((size_t)nfrag * 2 + 0) * 16 + kfg) * 512 + lane * 8];
        const f16x8 bl = *(const f16x8*)&wfO[(((size_t)nfrag * 2 + 1) * 16 + kfg) * 512 + lane * 8];
        acch = __builtin_amdgcn_mfma_f32_16x16x32_f16(A.v, bh, acch, 0, 0, 0);
        accl = __builtin_amdgcn_mfma_f32_16x16x32_f16(A.v, bl, accl, 0, 0, 0);
    }
    #pragma unroll
    for (int j = 0; j < 4; ++j) {
        float v = acch[j] + accl[j] * LO_INV;
        int row = fm * 32 + wm * 16 + lq * 4 + j;
        out[(size_t)row * (NSTEPS * 512) + (size_t)s * 512 + col] = v;
    }
}

// ---------------- persistent kernel ------------------------------------------
__global__ __launch_bounds__(256, 1) void persist(
    const ushort* __restrict__ xh,
    const ushort* __restrict__ wf0, const ushort* __restrict__ wf1,
    const ushort* __restrict__ wfO, const ushort* __restrict__ wfC,
    const float* __restrict__ b_ih, const float* __restrict__ b_hh,
    const float* __restrict__ b_out, const float* __restrict__ bcomb,
    ushort* h0a, ushort* h0b, ushort* h1a, ushort* h1b,
    float* out, unsigned* slots)
{
    __shared__ ushort sW[2][2][32][512];      // 128KB
    __shared__ ushort sA[2][128][64];         // 32KB

    const int tid = threadIdx.x;
    const int blk = blockIdx.x;
    const int half = blk >> 7;
    const int w = blk & 127;
    const int mblk = w >> 6, hcblk = w & 63;

    {
        const uint4* srcv = (const uint4*)((half ? wf1 : wf0) + (size_t)hcblk * 65536);
        uint4* dstv = (uint4*)&sW[0][0][0][0];
        #pragma unroll 1
        for (int i = tid; i < 8192; i += 256) dstv[i] = srcv[i];
    }

    float cReg[16];
    #pragma unroll
    for (int i = 0; i < 16; ++i) cReg[i] = 0.f;

    const int lane = tid & 63, wid = tid >> 6, wn = wid & 1;
    const int nloc = wn * 16 + (lane & 15);
    const int g = nloc & 3, hc = nloc >> 2;
    const int gcol = g * 512 + hcblk * 8 + hc;
    const float bias = b_ih[half * 2048 + gcol] + b_hh[half * 2048 + gcol];
    __syncthreads();

    ushort* h0buf[2] = {h0a, h0b};
    ushort* h1buf[2] = {h1a, h1b};
    unsigned nbar = 0;

    // ---- encode: 129 phases, layer-pipelined ----
    #pragma unroll 1
    for (int p = 0; p <= SS; ++p) {
        if (half == 0) {
            if (p < SS)
                run_cell(tid, mblk, hcblk, xh + (size_t)p * 512, (size_t)(SS * 512),
                         h0buf[p & 1], sW, sA, cReg, bias, h0buf[(p + 1) & 1]);
        } else {
            if (p >= 1) {
                int q = p - 1;
                run_cell(tid, mblk, hcblk, h0buf[p & 1], 512,
                         h1buf[q & 1], sW, sA, cReg, bias, h1buf[(q + 1) & 1]);
            }
        }
        gridbar(slots, ++nbar);
    }
    int h0cur = 0, h1cur = 0;

    // ---- transition: half0 swaps Wih0 -> Wcomb in LDS; bias += bcomb ----
    float biasDec = bias;
    if (half == 0) {
        const uint4* srcv = (const uint4*)(wfC + (size_t)hcblk * 32768);
        #pragma unroll 1
        for (int i = tid; i < 4096; i += 256) {
            int l8 = i & 63;
            int rest = i >> 6;          // (nf*2+pp)*16 + kfg
            int kfg = rest & 15, pp = (rest >> 4) & 1, nf = rest >> 5;
            *((uint4*)&sW[nf][pp][kfg][0] + l8) = srcv[i];
        }
        biasDec = bias + bcomb[gcol];
        __syncthreads();
    }

    // ---- decode: 2 phases/step (L0' || fc-out, then L1) ----
    #pragma unroll 1
    for (int s = 0; s < NSTEPS; ++s) {
        if (half == 0) {
            if (s < NSTEPS - 1)
                run_cell(tid, mblk, hcblk, h1buf[h1cur], 512, h0buf[h0cur],
                         sW, sA, cReg, biasDec, h0buf[h0cur ^ 1]);
        } else {
            run_fc(tid, w, h1buf[h1cur], wfO, b_out, out, s);
        }
        gridbar(slots, ++nbar);
        h0cur ^= 1;
        if (s == NSTEPS - 1) break;
        if (half == 1)
            run_cell(tid, mblk, hcblk, h0buf[h0cur], 512, h1buf[h1cur],
                     sW, sA, cReg, bias, h1buf[h1cur ^ 1]);
        gridbar(slots, ++nbar);
        h1cur ^= 1;
    }
}

// ---------------- host ---------------------------------------------------------
extern "C" void kernel_launch(void* const* d_in, const int* in_sizes, int n_in,
                              void* d_out, int out_size, void* d_ws, size_t ws_size,
                              hipStream_t stream)
{
    const float* x     = (const float*)d_in[0];
    const float* W_ih  = (const float*)d_in[1];
    const float* W_hh  = (const float*)d_in[2];
    const float* b_ih  = (const float*)d_in[3];
    const float* b_hh  = (const float*)d_in[4];
    const float* W_out = (const float*)d_in[5];
    const float* b_out = (const float*)d_in[6];
    float* out = (float*)d_out;
    (void)n_in; (void)out_size; (void)ws_size;

    char* ws = (char*)d_ws;
    ushort*   h0a   = (ushort*)(ws + 0);
    ushort*   h0b   = (ushort*)(ws + 262144);
    ushort*   h1a   = (ushort*)(ws + 524288);
    ushort*   h1b   = (ushort*)(ws + 786432);
    unsigned* slots = (unsigned*)(ws + 1048576);
    float*    bcomb = (float*)(ws + 1049600);
    const size_t ZBYTES = 1057792;
    ushort* xh    = (ushort*)(ws + 1057792);                 // 33.5MB
    ushort* wf0   = (ushort*)(ws + 1057792 + 33554432);
    ushort* wf1   = (ushort*)(ws + 1057792 + 33554432 + 8388608);
    ushort* wfO   = (ushort*)(ws + 1057792 + 33554432 + 2 * 8388608);
    float*  wcomb = (float*) (ws + 1057792 + 33554432 + 2 * 8388608 + 1048576);
    ushort* wfC   = (ushort*)(ws + 1057792 + 33554432 + 2 * 8388608 + 1048576 + 4194304);
    // total ws use ~58MB

    (void)hipMemsetAsync(d_ws, 0, ZBYTES, stream);
    {
        // x has in_sizes[0] = B*S*H elements; 8 per thread, 256 per block.
        int n8 = (in_sizes[0] + 7) / 8;                      // 2,097,152
        int blocks = (n8 + 255) / 256;                       // 8192
        xcvt<<<blocks, 256, 0, stream>>>(x, xh, n8);
    }
    wsplit_layers<<<2048, 256, 0, stream>>>(W_ih, W_hh, wf0, wf1);
    wsplit_out<<<128, 256, 0, stream>>>(W_out, wfO);
    gemm_wcomb<<<dim3(32, 8), 256, 0, stream>>>(W_ih, W_out, wcomb);
    bcomb_k<<<8, 256, 0, stream>>>(W_ih, b_out, bcomb);
    wsplit_wcomb<<<512, 256, 0, stream>>>(wcomb, wfC);

    persist<<<dim3(256), dim3(256), 0, stream>>>(
        xh, wf0, wf1, wfO, wfC, b_ih, b_hh, b_out, bcomb,
        h0a, h0b, h1a, h1b, out, slots);
}